// Round 2
// baseline (229.391 us; speedup 1.0000x reference)
//
#include <hip/hip_runtime.h>
#include <hip/hip_bf16.h>

#define NLAT 721
#define NLON 1440
#define NB 8
#define NROWS (NLAT - 1)          // 720 cell rows
#define NCELLS (NROWS * NLON)     // 1,036,800 cells

typedef float f32x2 __attribute__((ext_vector_type(2)));
typedef float f32x4 __attribute__((ext_vector_type(4)));

// ---- bf16 pack/unpack (RNE), consistent lo/hi convention -------------------
__device__ __forceinline__ unsigned pack2_bf16(float a, float b) {
    unsigned ua = __float_as_uint(a);
    unsigned ub = __float_as_uint(b);
    ua = (ua + 0x7FFFu + ((ua >> 16) & 1u)) >> 16;
    ub = (ub + 0x7FFFu + ((ub >> 16) & 1u)) >> 16;
    return ua | (ub << 16);
}
__device__ __forceinline__ float bf_lo(unsigned u) { return __uint_as_float(u << 16); }
__device__ __forceinline__ float bf_hi(unsigned u) { return __uint_as_float(u & 0xFFFF0000u); }

__device__ __forceinline__ uint4 pack8(const float* v) {
    return make_uint4(pack2_bf16(v[0], v[1]), pack2_bf16(v[2], v[3]),
                      pack2_bf16(v[4], v[5]), pack2_bf16(v[6], v[7]));
}

// r[0..7] = w * unpack(U)   (first term: plain mul, no zero-init fma chain)
__device__ __forceinline__ void mul8(float* r, float w, uint4 U) {
    r[0] = w * bf_lo(U.x);  r[1] = w * bf_hi(U.x);
    r[2] = w * bf_lo(U.y);  r[3] = w * bf_hi(U.y);
    r[4] = w * bf_lo(U.z);  r[5] = w * bf_hi(U.z);
    r[6] = w * bf_lo(U.w);  r[7] = w * bf_hi(U.w);
}

// accumulate r[0..7] += w * unpack(U)
__device__ __forceinline__ void accum8(float* r, float w, uint4 U) {
    r[0] = fmaf(w, bf_lo(U.x), r[0]);  r[1] = fmaf(w, bf_hi(U.x), r[1]);
    r[2] = fmaf(w, bf_lo(U.y), r[2]);  r[3] = fmaf(w, bf_hi(U.y), r[3]);
    r[4] = fmaf(w, bf_lo(U.z), r[4]);  r[5] = fmaf(w, bf_hi(U.z), r[5]);
    r[6] = fmaf(w, bf_lo(U.w), r[6]);  r[7] = fmaf(w, bf_hi(U.w), r[7]);
}

__device__ __forceinline__ void store_out_nt(float* out, size_t n, const float* r) {
    f32x4 o0 = {r[0], r[1], r[2], r[3]};
    f32x4 o1 = {r[4], r[5], r[6], r[7]};
    f32x4* o = (f32x4*)(out + n * NB);
    __builtin_nontemporal_store(o0, o);
    __builtin_nontemporal_store(o1, o + 1);
}

// Shared helper: locate lat cell + weights (lat grid is uniform linspace;
// the while loops only correct float-rounding edge cases).
__device__ __forceinline__ void lat_cell(const float* s_lat, float lat,
                                         int& j, float& wlat) {
    j = (int)floorf((lat + 90.0f) * 4.0f);
    j = min(max(j, 0), NLAT - 2);
    while (j > 0 && lat < s_lat[j]) --j;
    while (j < NLAT - 2 && lat >= s_lat[j + 1]) ++j;
    float l0 = s_lat[j], l1 = s_lat[j + 1];
    wlat = (lat - l0) / (l1 - l0);
}

__device__ __forceinline__ void lon_cell(float lon, int& i, float& wlon) {
    float lon4 = lon * 4.0f;
    i = (int)floorf(lon4);
    i = min(max(i, 0), NLON - 1);
    wlon = lon4 - (float)i;
}

// ---------------------------------------------------------------------------
// Build pass (preferred): xc[cell] = 64 B record {v00[8], v10[8], v01[8], v11[8]}
// in bf16, wrap column baked in. Thread-per-cell; plane reads coalesce across
// lanes (i contiguous), the +1-shifted stream hits the same lines (L1).
// Stores stay CACHEABLE on purpose: the gather wants this table L2/L3-resident.
// ---------------------------------------------------------------------------
__global__ __launch_bounds__(256) void build_cells_kernel(
    const float* __restrict__ x,   // [NB, NLAT, NLON]
    uint4* __restrict__ xc)        // [NCELLS, 4] (64 B per cell)
{
    int t = blockIdx.x * blockDim.x + threadIdx.x;
    if (t >= NCELLS) return;
    int j = t / NLON;
    int i = t - j * NLON;
    int i1 = (i == NLON - 1) ? 0 : i + 1;

    float v00[NB], v10[NB], v01[NB], v11[NB];
#pragma unroll
    for (int b = 0; b < NB; ++b) {
        const float* pb = x + ((size_t)b * NLAT + j) * NLON;
        v00[b] = pb[i];
        v10[b] = pb[i1];
        v01[b] = pb[NLON + i];
        v11[b] = pb[NLON + i1];
    }
    uint4* o = xc + (size_t)t * 4;
    o[0] = pack8(v00);
    o[1] = pack8(v10);
    o[2] = pack8(v01);
    o[3] = pack8(v11);
}

// ---------------------------------------------------------------------------
// Gather (preferred): 2 points per thread, chunk-interleaved so xi/out stay
// lane-coalesced while each thread keeps TWO independent 64 B record fetches
// in flight (MLP). xi loads + out stores are NON-TEMPORAL: zero-reuse streams
// must not evict the xc table from L2/L3.
// ---------------------------------------------------------------------------
__global__ __launch_bounds__(256) void regrid_cells_kernel(
    const uint4* __restrict__ xc,
    const float* __restrict__ lat_src,
    const float* __restrict__ xi,
    float* __restrict__ out,
    int N)
{
    __shared__ float s_lat[NLAT];
    for (int t = threadIdx.x; t < NLAT; t += blockDim.x) s_lat[t] = lat_src[t];
    __syncthreads();

    int base = blockIdx.x * (blockDim.x * 2);
    int n0 = base + threadIdx.x;              // point 1
    int n1 = n0 + blockDim.x;                 // point 2 (independent)
    if (n0 >= N) return;
    bool has2 = (n1 < N);

    f32x2 q0 = __builtin_nontemporal_load(((const f32x2*)xi) + n0);
    f32x2 q1 = has2 ? __builtin_nontemporal_load(((const f32x2*)xi) + n1)
                    : q0;

    int i0, i1p, j0, j1;
    float wlon0, wlon1, wlat0, wlat1;
    lon_cell(q0.x, i0, wlon0);
    lon_cell(q1.x, i1p, wlon1);
    lat_cell(s_lat, q0.y, j0, wlat0);
    lat_cell(s_lat, q1.y, j1, wlat1);

    // Issue both record fetches back-to-back: 8 independent dwordx4 in flight.
    const uint4* cp0 = xc + (size_t)(j0 * NLON + i0) * 4;
    const uint4* cp1 = xc + (size_t)(j1 * NLON + i1p) * 4;
    uint4 A0 = cp0[0], B0 = cp0[1], C0 = cp0[2], D0 = cp0[3];
    uint4 A1 = cp1[0], B1 = cp1[1], C1 = cp1[2], D1 = cp1[3];

    float alat0 = 1.0f - wlat0, alon0 = 1.0f - wlon0;
    float alat1 = 1.0f - wlat1, alon1 = 1.0f - wlon1;

    float r0[NB], r1[NB];
    mul8  (r0, alat0 * alon0, A0);
    accum8(r0, alat0 * wlon0, B0);
    accum8(r0, wlat0 * alon0, C0);
    accum8(r0, wlat0 * wlon0, D0);
    store_out_nt(out, (size_t)n0, r0);

    if (has2) {
        mul8  (r1, alat1 * alon1, A1);
        accum8(r1, alat1 * wlon1, B1);
        accum8(r1, wlat1 * alon1, C1);
        accum8(r1, wlat1 * wlon1, D1);
        store_out_nt(out, (size_t)n1, r1);
    }
}

// ---------------------------------------------------------------------------
// Mid path (ws >= 33 MB): packed row-pair nodes, 32 B per node, 2 sectors/pt.
// ---------------------------------------------------------------------------
__global__ __launch_bounds__(256) void build_pairs_kernel(
    const float* __restrict__ x,
    uint4* __restrict__ xp)        // [NROWS*NLON, 2] (32 B per node)
{
    int t = blockIdx.x * blockDim.x + threadIdx.x;
    if (t >= NCELLS) return;
    int j = t / NLON;
    int i = t - j * NLON;

    float v0[NB], v1[NB];
#pragma unroll
    for (int b = 0; b < NB; ++b) {
        const float* pb = x + ((size_t)b * NLAT + j) * NLON;
        v0[b] = pb[i];
        v1[b] = pb[NLON + i];
    }
    uint4* o = xp + (size_t)t * 2;
    o[0] = pack8(v0);
    o[1] = pack8(v1);
}

__global__ __launch_bounds__(256) void regrid_pairs_kernel(
    const uint4* __restrict__ xp,
    const float* __restrict__ lat_src,
    const float* __restrict__ xi,
    float* __restrict__ out,
    int N)
{
    __shared__ float s_lat[NLAT];
    for (int t = threadIdx.x; t < NLAT; t += blockDim.x) s_lat[t] = lat_src[t];
    __syncthreads();

    int n = blockIdx.x * blockDim.x + threadIdx.x;
    if (n >= N) return;

    f32x2 q = __builtin_nontemporal_load(((const f32x2*)xi) + n);

    int i, j;
    float wlon, wlat;
    lon_cell(q.x, i, wlon);
    lat_cell(s_lat, q.y, j, wlat);
    int i1 = (i == NLON - 1) ? 0 : i + 1;
    float alat = 1.0f - wlat, alon = 1.0f - wlon;

    const uint4* p0 = xp + (size_t)(j * NLON + i) * 2;
    const uint4* p1 = xp + (size_t)(j * NLON + i1) * 2;
    uint4 A = p0[0], C = p0[1];   // col i : row j, row j+1
    uint4 B = p1[0], D = p1[1];   // col i1: row j, row j+1

    float r[NB];
    mul8  (r, alat * alon, A);
    accum8(r, alat * wlon, B);
    accum8(r, wlat * alon, C);
    accum8(r, wlat * wlon, D);

    store_out_nt(out, (size_t)n, r);
}

// ---------------------------------------------------------------------------
// Last-resort fallback (no workspace): R0 direct kernel, fp32 exact.
// ---------------------------------------------------------------------------
__global__ __launch_bounds__(256) void regrid_direct_kernel(
    const float* __restrict__ x,
    const float* __restrict__ lat_src,
    const float* __restrict__ xi,
    float* __restrict__ out,
    int N)
{
    __shared__ float s_lat[NLAT];
    for (int t = threadIdx.x; t < NLAT; t += blockDim.x) s_lat[t] = lat_src[t];
    __syncthreads();

    int n = blockIdx.x * blockDim.x + threadIdx.x;
    if (n >= N) return;

    f32x2 q = __builtin_nontemporal_load(((const f32x2*)xi) + n);

    int i, j;
    float wlon, wlat;
    lon_cell(q.x, i, wlon);
    lat_cell(s_lat, q.y, j, wlat);
    int i1 = (i == NLON - 1) ? 0 : i + 1;
    float alat = 1.0f - wlat, alon = 1.0f - wlon;

    float res[NB];
#pragma unroll
    for (int b = 0; b < NB; ++b) {
        const float* row0 = x + ((size_t)b * NLAT + j) * NLON;
        const float* row1 = row0 + NLON;
        res[b] = alat * (alon * row0[i] + wlon * row0[i1])
               + wlat * (alon * row1[i] + wlon * row1[i1]);
    }
    store_out_nt(out, (size_t)n, res);
}

extern "C" void kernel_launch(void* const* d_in, const int* in_sizes, int n_in,
                              void* d_out, int out_size, void* d_ws, size_t ws_size,
                              hipStream_t stream) {
    const float* x       = (const float*)d_in[0];
    const float* lat_src = (const float*)d_in[2];
    const float* xi      = (const float*)d_in[3];
    float* out           = (float*)d_out;

    int N = in_sizes[3] / 2;
    const size_t cell_bytes = (size_t)NCELLS * 64;   // 66.4 MB
    const size_t pair_bytes = (size_t)NCELLS * 32;   // 33.2 MB

    int bgrid = (NCELLS + 255) / 256;
    int ggrid  = (N + 255) / 256;
    int ggrid2 = (N + 511) / 512;   // 2 points per thread

    if (ws_size >= cell_bytes) {
        uint4* xc = (uint4*)d_ws;
        build_cells_kernel<<<bgrid, 256, 0, stream>>>(x, xc);
        regrid_cells_kernel<<<ggrid2, 256, 0, stream>>>(xc, lat_src, xi, out, N);
    } else if (ws_size >= pair_bytes) {
        uint4* xp = (uint4*)d_ws;
        build_pairs_kernel<<<bgrid, 256, 0, stream>>>(x, xp);
        regrid_pairs_kernel<<<ggrid, 256, 0, stream>>>(xp, lat_src, xi, out, N);
    } else {
        regrid_direct_kernel<<<ggrid, 256, 0, stream>>>(x, lat_src, xi, out, N);
    }
}

// Round 11
// 228.859 us; speedup vs baseline: 1.0023x; 1.0023x over previous
//
#include <hip/hip_runtime.h>
#include <hip/hip_bf16.h>

#define NLAT 721
#define NLON 1440
#define NB 8
#define NROWS (NLAT - 1)          // 720 cell rows
#define NCELLS (NROWS * NLON)     // 1,036,800 cells

typedef float f32x2 __attribute__((ext_vector_type(2)));
typedef float f32x4 __attribute__((ext_vector_type(4)));

// ---- bf16 pack/unpack (RNE), consistent lo/hi convention -------------------
__device__ __forceinline__ unsigned pack2_bf16(float a, float b) {
    unsigned ua = __float_as_uint(a);
    unsigned ub = __float_as_uint(b);
    ua = (ua + 0x7FFFu + ((ua >> 16) & 1u)) >> 16;
    ub = (ub + 0x7FFFu + ((ub >> 16) & 1u)) >> 16;
    return ua | (ub << 16);
}
__device__ __forceinline__ float bf_lo(unsigned u) { return __uint_as_float(u << 16); }
__device__ __forceinline__ float bf_hi(unsigned u) { return __uint_as_float(u & 0xFFFF0000u); }

__device__ __forceinline__ uint4 pack8(const float* v) {
    return make_uint4(pack2_bf16(v[0], v[1]), pack2_bf16(v[2], v[3]),
                      pack2_bf16(v[4], v[5]), pack2_bf16(v[6], v[7]));
}

// r[0..7] = w * unpack(U)   (first term: plain mul, no zero-init fma chain)
__device__ __forceinline__ void mul8(float* r, float w, uint4 U) {
    r[0] = w * bf_lo(U.x);  r[1] = w * bf_hi(U.x);
    r[2] = w * bf_lo(U.y);  r[3] = w * bf_hi(U.y);
    r[4] = w * bf_lo(U.z);  r[5] = w * bf_hi(U.z);
    r[6] = w * bf_lo(U.w);  r[7] = w * bf_hi(U.w);
}

// accumulate r[0..7] += w * unpack(U)
__device__ __forceinline__ void accum8(float* r, float w, uint4 U) {
    r[0] = fmaf(w, bf_lo(U.x), r[0]);  r[1] = fmaf(w, bf_hi(U.x), r[1]);
    r[2] = fmaf(w, bf_lo(U.y), r[2]);  r[3] = fmaf(w, bf_hi(U.y), r[3]);
    r[4] = fmaf(w, bf_lo(U.z), r[4]);  r[5] = fmaf(w, bf_hi(U.z), r[5]);
    r[6] = fmaf(w, bf_lo(U.w), r[6]);  r[7] = fmaf(w, bf_hi(U.w), r[7]);
}

__device__ __forceinline__ void store_out_nt(float* out, size_t n, const float* r) {
    f32x4 o0 = {r[0], r[1], r[2], r[3]};
    f32x4 o1 = {r[4], r[5], r[6], r[7]};
    f32x4* o = (f32x4*)(out + n * NB);
    __builtin_nontemporal_store(o0, o);
    __builtin_nontemporal_store(o1, o + 1);
}

// Shared helper: locate lat cell + weights (lat grid is uniform linspace;
// the while loops only correct float-rounding edge cases).
__device__ __forceinline__ void lat_cell(const float* s_lat, float lat,
                                         int& j, float& wlat) {
    j = (int)floorf((lat + 90.0f) * 4.0f);
    j = min(max(j, 0), NLAT - 2);
    while (j > 0 && lat < s_lat[j]) --j;
    while (j < NLAT - 2 && lat >= s_lat[j + 1]) ++j;
    float l0 = s_lat[j], l1 = s_lat[j + 1];
    wlat = (lat - l0) / (l1 - l0);
}

__device__ __forceinline__ void lon_cell(float lon, int& i, float& wlon) {
    float lon4 = lon * 4.0f;
    i = (int)floorf(lon4);
    i = min(max(i, 0), NLON - 1);
    wlon = lon4 - (float)i;
}

// ---------------------------------------------------------------------------
// Build pass (preferred): xc[cell] = 64 B record {v00[8], v10[8], v01[8], v11[8]}
// in bf16, wrap column baked in.
// Thread-per-record-QUARTER (4 threads per cell): each thread loads one corner
// for all 8 batches, packs one uint4, stores at xc_flat[k].
//   - stores: lane k writes 16 B at byte 16*k -> perfectly contiguous 1 KB/wave
//     per store instruction (the old layout wrote 16 B/lane at 64 B stride,
//     touching 64 lines per instruction = write-coalescing penalty).
//   - loads: per instruction a wave touches ~2 grid rows x 17 floats -> L1 hits.
// Stores stay CACHEABLE on purpose: the gather wants this table L2/L3-resident.
// ---------------------------------------------------------------------------
__global__ __launch_bounds__(256) void build_cells_kernel(
    const float* __restrict__ x,   // [NB, NLAT, NLON]
    uint4* __restrict__ xc)        // [NCELLS*4] quarters (64 B per cell)
{
    int k = blockIdx.x * blockDim.x + threadIdx.x;
    if (k >= NCELLS * 4) return;
    int cell = k >> 2;
    int part = k & 3;
    int j = cell / NLON;
    int i = cell - j * NLON;

    int row = j + (part >> 1);                      // 0,1 -> j ; 2,3 -> j+1
    int col = (part & 1) ? ((i == NLON - 1) ? 0 : i + 1) : i;

    float v[NB];
#pragma unroll
    for (int b = 0; b < NB; ++b)
        v[b] = x[((size_t)b * NLAT + row) * NLON + col];

    xc[k] = pack8(v);
}

// ---------------------------------------------------------------------------
// Gather (preferred): 2 points per thread, chunk-interleaved so xi/out stay
// lane-coalesced while each thread keeps TWO independent 64 B record fetches
// in flight (MLP). xi loads + out stores are NON-TEMPORAL: zero-reuse streams
// must not evict the xc table from L2/L3.
// ---------------------------------------------------------------------------
__global__ __launch_bounds__(256) void regrid_cells_kernel(
    const uint4* __restrict__ xc,
    const float* __restrict__ lat_src,
    const float* __restrict__ xi,
    float* __restrict__ out,
    int N)
{
    __shared__ float s_lat[NLAT];
    for (int t = threadIdx.x; t < NLAT; t += blockDim.x) s_lat[t] = lat_src[t];
    __syncthreads();

    int base = blockIdx.x * (blockDim.x * 2);
    int n0 = base + threadIdx.x;              // point 1
    int n1 = n0 + blockDim.x;                 // point 2 (independent)
    if (n0 >= N) return;
    bool has2 = (n1 < N);

    f32x2 q0 = __builtin_nontemporal_load(((const f32x2*)xi) + n0);
    f32x2 q1 = has2 ? __builtin_nontemporal_load(((const f32x2*)xi) + n1)
                    : q0;

    int i0, i1p, j0, j1;
    float wlon0, wlon1, wlat0, wlat1;
    lon_cell(q0.x, i0, wlon0);
    lon_cell(q1.x, i1p, wlon1);
    lat_cell(s_lat, q0.y, j0, wlat0);
    lat_cell(s_lat, q1.y, j1, wlat1);

    // Issue both record fetches back-to-back: 8 independent dwordx4 in flight.
    const uint4* cp0 = xc + (size_t)(j0 * NLON + i0) * 4;
    const uint4* cp1 = xc + (size_t)(j1 * NLON + i1p) * 4;
    uint4 A0 = cp0[0], B0 = cp0[1], C0 = cp0[2], D0 = cp0[3];
    uint4 A1 = cp1[0], B1 = cp1[1], C1 = cp1[2], D1 = cp1[3];

    float alat0 = 1.0f - wlat0, alon0 = 1.0f - wlon0;
    float alat1 = 1.0f - wlat1, alon1 = 1.0f - wlon1;

    float r0[NB], r1[NB];
    mul8  (r0, alat0 * alon0, A0);
    accum8(r0, alat0 * wlon0, B0);
    accum8(r0, wlat0 * alon0, C0);
    accum8(r0, wlat0 * wlon0, D0);
    store_out_nt(out, (size_t)n0, r0);

    if (has2) {
        mul8  (r1, alat1 * alon1, A1);
        accum8(r1, alat1 * wlon1, B1);
        accum8(r1, wlat1 * alon1, C1);
        accum8(r1, wlat1 * wlon1, D1);
        store_out_nt(out, (size_t)n1, r1);
    }
}

// ---------------------------------------------------------------------------
// Mid path (ws >= 33 MB): packed row-pair nodes, 32 B per node, 2 sectors/pt.
// ---------------------------------------------------------------------------
__global__ __launch_bounds__(256) void build_pairs_kernel(
    const float* __restrict__ x,
    uint4* __restrict__ xp)        // [NROWS*NLON, 2] (32 B per node)
{
    int k = blockIdx.x * blockDim.x + threadIdx.x;
    if (k >= NCELLS * 2) return;
    int cell = k >> 1;
    int part = k & 1;
    int j = cell / NLON;
    int i = cell - j * NLON;
    int row = j + part;

    float v[NB];
#pragma unroll
    for (int b = 0; b < NB; ++b)
        v[b] = x[((size_t)b * NLAT + row) * NLON + i];

    xp[k] = pack8(v);
}

__global__ __launch_bounds__(256) void regrid_pairs_kernel(
    const uint4* __restrict__ xp,
    const float* __restrict__ lat_src,
    const float* __restrict__ xi,
    float* __restrict__ out,
    int N)
{
    __shared__ float s_lat[NLAT];
    for (int t = threadIdx.x; t < NLAT; t += blockDim.x) s_lat[t] = lat_src[t];
    __syncthreads();

    int n = blockIdx.x * blockDim.x + threadIdx.x;
    if (n >= N) return;

    f32x2 q = __builtin_nontemporal_load(((const f32x2*)xi) + n);

    int i, j;
    float wlon, wlat;
    lon_cell(q.x, i, wlon);
    lat_cell(s_lat, q.y, j, wlat);
    int i1 = (i == NLON - 1) ? 0 : i + 1;
    float alat = 1.0f - wlat, alon = 1.0f - wlon;

    const uint4* p0 = xp + (size_t)(j * NLON + i) * 2;
    const uint4* p1 = xp + (size_t)(j * NLON + i1) * 2;
    uint4 A = p0[0], C = p0[1];   // col i : row j, row j+1
    uint4 B = p1[0], D = p1[1];   // col i1: row j, row j+1

    float r[NB];
    mul8  (r, alat * alon, A);
    accum8(r, alat * wlon, B);
    accum8(r, wlat * alon, C);
    accum8(r, wlat * wlon, D);

    store_out_nt(out, (size_t)n, r);
}

// ---------------------------------------------------------------------------
// Last-resort fallback (no workspace): R0 direct kernel, fp32 exact.
// ---------------------------------------------------------------------------
__global__ __launch_bounds__(256) void regrid_direct_kernel(
    const float* __restrict__ x,
    const float* __restrict__ lat_src,
    const float* __restrict__ xi,
    float* __restrict__ out,
    int N)
{
    __shared__ float s_lat[NLAT];
    for (int t = threadIdx.x; t < NLAT; t += blockDim.x) s_lat[t] = lat_src[t];
    __syncthreads();

    int n = blockIdx.x * blockDim.x + threadIdx.x;
    if (n >= N) return;

    f32x2 q = __builtin_nontemporal_load(((const f32x2*)xi) + n);

    int i, j;
    float wlon, wlat;
    lon_cell(q.x, i, wlon);
    lat_cell(s_lat, q.y, j, wlat);
    int i1 = (i == NLON - 1) ? 0 : i + 1;
    float alat = 1.0f - wlat, alon = 1.0f - wlon;

    float res[NB];
#pragma unroll
    for (int b = 0; b < NB; ++b) {
        const float* row0 = x + ((size_t)b * NLAT + j) * NLON;
        const float* row1 = row0 + NLON;
        res[b] = alat * (alon * row0[i] + wlon * row0[i1])
               + wlat * (alon * row1[i] + wlon * row1[i1]);
    }
    store_out_nt(out, (size_t)n, res);
}

extern "C" void kernel_launch(void* const* d_in, const int* in_sizes, int n_in,
                              void* d_out, int out_size, void* d_ws, size_t ws_size,
                              hipStream_t stream) {
    const float* x       = (const float*)d_in[0];
    const float* lat_src = (const float*)d_in[2];
    const float* xi      = (const float*)d_in[3];
    float* out           = (float*)d_out;

    int N = in_sizes[3] / 2;
    const size_t cell_bytes = (size_t)NCELLS * 64;   // 66.4 MB
    const size_t pair_bytes = (size_t)NCELLS * 32;   // 33.2 MB

    int ggrid  = (N + 255) / 256;
    int ggrid2 = (N + 511) / 512;   // 2 points per thread

    if (ws_size >= cell_bytes) {
        uint4* xc = (uint4*)d_ws;
        int bgrid4 = (NCELLS * 4 + 255) / 256;       // thread per 16 B quarter
        build_cells_kernel<<<bgrid4, 256, 0, stream>>>(x, xc);
        regrid_cells_kernel<<<ggrid2, 256, 0, stream>>>(xc, lat_src, xi, out, N);
    } else if (ws_size >= pair_bytes) {
        uint4* xp = (uint4*)d_ws;
        int bgrid2 = (NCELLS * 2 + 255) / 256;       // thread per 16 B half
        build_pairs_kernel<<<bgrid2, 256, 0, stream>>>(x, xp);
        regrid_pairs_kernel<<<ggrid, 256, 0, stream>>>(xp, lat_src, xi, out, N);
    } else {
        regrid_direct_kernel<<<ggrid, 256, 0, stream>>>(x, lat_src, xi, out, N);
    }
}

// Round 12
// 224.661 us; speedup vs baseline: 1.0211x; 1.0187x over previous
//
#include <hip/hip_runtime.h>
#include <hip/hip_bf16.h>

#define NLAT 721
#define NLON 1440
#define NB 8
#define NROWS (NLAT - 1)          // 720 cell rows
#define NCELLS (NROWS * NLON)     // 1,036,800 cells

typedef float f32x2 __attribute__((ext_vector_type(2)));
typedef float f32x4 __attribute__((ext_vector_type(4)));

// ---- bf16 pack/unpack (RNE), consistent lo/hi convention -------------------
__device__ __forceinline__ unsigned pack2_bf16(float a, float b) {
    unsigned ua = __float_as_uint(a);
    unsigned ub = __float_as_uint(b);
    ua = (ua + 0x7FFFu + ((ua >> 16) & 1u)) >> 16;
    ub = (ub + 0x7FFFu + ((ub >> 16) & 1u)) >> 16;
    return ua | (ub << 16);
}
__device__ __forceinline__ float bf_lo(unsigned u) { return __uint_as_float(u << 16); }
__device__ __forceinline__ float bf_hi(unsigned u) { return __uint_as_float(u & 0xFFFF0000u); }

__device__ __forceinline__ uint4 pack8(const float* v) {
    return make_uint4(pack2_bf16(v[0], v[1]), pack2_bf16(v[2], v[3]),
                      pack2_bf16(v[4], v[5]), pack2_bf16(v[6], v[7]));
}

// r[0..7] = w * unpack(U)
__device__ __forceinline__ void mul8(float* r, float w, uint4 U) {
    r[0] = w * bf_lo(U.x);  r[1] = w * bf_hi(U.x);
    r[2] = w * bf_lo(U.y);  r[3] = w * bf_hi(U.y);
    r[4] = w * bf_lo(U.z);  r[5] = w * bf_hi(U.z);
    r[6] = w * bf_lo(U.w);  r[7] = w * bf_hi(U.w);
}

// accumulate r[0..7] += w * unpack(U)
__device__ __forceinline__ void accum8(float* r, float w, uint4 U) {
    r[0] = fmaf(w, bf_lo(U.x), r[0]);  r[1] = fmaf(w, bf_hi(U.x), r[1]);
    r[2] = fmaf(w, bf_lo(U.y), r[2]);  r[3] = fmaf(w, bf_hi(U.y), r[3]);
    r[4] = fmaf(w, bf_lo(U.z), r[4]);  r[5] = fmaf(w, bf_hi(U.z), r[5]);
    r[6] = fmaf(w, bf_lo(U.w), r[6]);  r[7] = fmaf(w, bf_hi(U.w), r[7]);
}

__device__ __forceinline__ void store_out_nt(float* out, size_t n, const float* r) {
    f32x4 o0 = {r[0], r[1], r[2], r[3]};
    f32x4 o1 = {r[4], r[5], r[6], r[7]};
    f32x4* o = (f32x4*)(out + n * NB);
    __builtin_nontemporal_store(o0, o);
    __builtin_nontemporal_store(o1, o + 1);
}

// Shared helper: locate lat cell + weights (lat grid is uniform linspace;
// the while loops only correct float-rounding edge cases).
__device__ __forceinline__ void lat_cell(const float* s_lat, float lat,
                                         int& j, float& wlat) {
    j = (int)floorf((lat + 90.0f) * 4.0f);
    j = min(max(j, 0), NLAT - 2);
    while (j > 0 && lat < s_lat[j]) --j;
    while (j < NLAT - 2 && lat >= s_lat[j + 1]) ++j;
    float l0 = s_lat[j], l1 = s_lat[j + 1];
    wlat = (lat - l0) / (l1 - l0);
}

__device__ __forceinline__ void lon_cell(float lon, int& i, float& wlon) {
    float lon4 = lon * 4.0f;
    i = (int)floorf(lon4);
    i = min(max(i, 0), NLON - 1);
    wlon = lon4 - (float)i;
}

// ---------------------------------------------------------------------------
// Build (primary): packed row-pair nodes, 32 B per node.
// Node (j,i) = {x[b][j][i] (8 bf16), x[b][j+1][i] (8 bf16)}.
// A point (j,i) reads nodes (j,i) and (j,i1): 2 adjacent 32 B sectors -> same
// 64 B/point sector traffic as the cell table, but the table is HALF the size
// (33 MB ~ aggregate L2), so L2/L3 hit rates roughly double.
// Thread-per-16 B-half: stores perfectly contiguous 1 KB/wave; loads span
// ~2 grid rows x ~33 floats per wave-instruction (L1-friendly).
// Stores CACHEABLE on purpose: gather wants the table resident.
// ---------------------------------------------------------------------------
__global__ __launch_bounds__(256) void build_pairs_kernel(
    const float* __restrict__ x,   // [NB, NLAT, NLON]
    uint4* __restrict__ xp)        // [NCELLS*2] halves (32 B per node)
{
    int k = blockIdx.x * blockDim.x + threadIdx.x;
    if (k >= NCELLS * 2) return;
    int cell = k >> 1;
    int part = k & 1;
    int j = cell / NLON;
    int i = cell - j * NLON;
    int row = j + part;

    float v[NB];
#pragma unroll
    for (int b = 0; b < NB; ++b)
        v[b] = x[((size_t)b * NLAT + row) * NLON + i];

    xp[k] = pack8(v);
}

// ---------------------------------------------------------------------------
// Gather (primary): 2 points per thread, chunk-interleaved (xi/out coalesced,
// each thread keeps 2 independent node-pair fetches in flight). xi loads and
// out stores NON-TEMPORAL (zero-reuse streams must not evict the table).
// ---------------------------------------------------------------------------
__global__ __launch_bounds__(256) void regrid_pairs_kernel(
    const uint4* __restrict__ xp,
    const float* __restrict__ lat_src,
    const float* __restrict__ xi,
    float* __restrict__ out,
    int N)
{
    __shared__ float s_lat[NLAT];
    for (int t = threadIdx.x; t < NLAT; t += blockDim.x) s_lat[t] = lat_src[t];
    __syncthreads();

    int base = blockIdx.x * (blockDim.x * 2);
    int n0 = base + threadIdx.x;              // point 1
    int n1 = n0 + blockDim.x;                 // point 2 (independent)
    if (n0 >= N) return;
    bool has2 = (n1 < N);

    f32x2 q0 = __builtin_nontemporal_load(((const f32x2*)xi) + n0);
    f32x2 q1 = has2 ? __builtin_nontemporal_load(((const f32x2*)xi) + n1)
                    : q0;

    int ia0, ia1, j0, j1;
    float wlon0, wlon1, wlat0, wlat1;
    lon_cell(q0.x, ia0, wlon0);
    lon_cell(q1.x, ia1, wlon1);
    lat_cell(s_lat, q0.y, j0, wlat0);
    lat_cell(s_lat, q1.y, j1, wlat1);
    int ib0 = (ia0 == NLON - 1) ? 0 : ia0 + 1;
    int ib1 = (ia1 == NLON - 1) ? 0 : ia1 + 1;

    // Issue all 8 node fetches back-to-back (4 per point, 2 bases per point).
    const uint4* pa0 = xp + (size_t)(j0 * NLON + ia0) * 2;
    const uint4* pb0 = xp + (size_t)(j0 * NLON + ib0) * 2;
    const uint4* pa1 = xp + (size_t)(j1 * NLON + ia1) * 2;
    const uint4* pb1 = xp + (size_t)(j1 * NLON + ib1) * 2;
    uint4 A0 = pa0[0], C0 = pa0[1];   // col i : row j, row j+1
    uint4 B0 = pb0[0], D0 = pb0[1];   // col i1: row j, row j+1
    uint4 A1 = pa1[0], C1 = pa1[1];
    uint4 B1 = pb1[0], D1 = pb1[1];

    float alat0 = 1.0f - wlat0, alon0 = 1.0f - wlon0;
    float alat1 = 1.0f - wlat1, alon1 = 1.0f - wlon1;

    float r0[NB], r1[NB];
    mul8  (r0, alat0 * alon0, A0);
    accum8(r0, alat0 * wlon0, B0);
    accum8(r0, wlat0 * alon0, C0);
    accum8(r0, wlat0 * wlon0, D0);
    store_out_nt(out, (size_t)n0, r0);

    if (has2) {
        mul8  (r1, alat1 * alon1, A1);
        accum8(r1, alat1 * wlon1, B1);
        accum8(r1, wlat1 * alon1, C1);
        accum8(r1, wlat1 * wlon1, D1);
        store_out_nt(out, (size_t)n1, r1);
    }
}

// ---------------------------------------------------------------------------
// Last-resort fallback (no workspace): direct kernel, fp32 exact.
// ---------------------------------------------------------------------------
__global__ __launch_bounds__(256) void regrid_direct_kernel(
    const float* __restrict__ x,
    const float* __restrict__ lat_src,
    const float* __restrict__ xi,
    float* __restrict__ out,
    int N)
{
    __shared__ float s_lat[NLAT];
    for (int t = threadIdx.x; t < NLAT; t += blockDim.x) s_lat[t] = lat_src[t];
    __syncthreads();

    int n = blockIdx.x * blockDim.x + threadIdx.x;
    if (n >= N) return;

    f32x2 q = __builtin_nontemporal_load(((const f32x2*)xi) + n);

    int i, j;
    float wlon, wlat;
    lon_cell(q.x, i, wlon);
    lat_cell(s_lat, q.y, j, wlat);
    int i1 = (i == NLON - 1) ? 0 : i + 1;
    float alat = 1.0f - wlat, alon = 1.0f - wlon;

    float res[NB];
#pragma unroll
    for (int b = 0; b < NB; ++b) {
        const float* row0 = x + ((size_t)b * NLAT + j) * NLON;
        const float* row1 = row0 + NLON;
        res[b] = alat * (alon * row0[i] + wlon * row0[i1])
               + wlat * (alon * row1[i] + wlon * row1[i1]);
    }
    store_out_nt(out, (size_t)n, res);
}

extern "C" void kernel_launch(void* const* d_in, const int* in_sizes, int n_in,
                              void* d_out, int out_size, void* d_ws, size_t ws_size,
                              hipStream_t stream) {
    const float* x       = (const float*)d_in[0];
    const float* lat_src = (const float*)d_in[2];
    const float* xi      = (const float*)d_in[3];
    float* out           = (float*)d_out;

    int N = in_sizes[3] / 2;
    const size_t pair_bytes = (size_t)NCELLS * 32;   // 33.2 MB

    int ggrid  = (N + 255) / 256;
    int ggrid2 = (N + 511) / 512;   // 2 points per thread

    if (ws_size >= pair_bytes) {
        uint4* xp = (uint4*)d_ws;
        int bgrid2 = (NCELLS * 2 + 255) / 256;       // thread per 16 B half
        build_pairs_kernel<<<bgrid2, 256, 0, stream>>>(x, xp);
        regrid_pairs_kernel<<<ggrid2, 256, 0, stream>>>(xp, lat_src, xi, out, N);
    } else {
        regrid_direct_kernel<<<ggrid, 256, 0, stream>>>(x, lat_src, xi, out, N);
    }
}